// Round 10
// baseline (181.330 us; speedup 1.0000x reference)
//
#include <hip/hip_runtime.h>
#include <hip/hip_bf16.h>
#include <hip/hip_cooperative_groups.h>
namespace cg = cooperative_groups;

// KAN linear == GEMM M=8192, N=512, K=4096 (8 Chebyshev/silu feats per input,
// basis_0 folded into bias). Round 19: gemm is pinned at its 2-phase ceiling
// (8 structures, 60-67us, all pipes <40%). The never-measured term is the
// OTHER ~64us: kan_prep dispatch + inter-launch + harness resets (constant
// across all 10 rounds). R19 removes everything kernel-side removable: ONE
// cooperative kernel = prep phase -> grid.sync -> gemm phase (verbatim R17).
// nb=XCD mapping makes the fusion coherence-trivial: block bid=(k8,t) preps
// row o=k8*64+t and the gemm on XCD k8 consumes exactly rows [k8*64,+64) --
// produced on the same XCD, L2-coherent; grid.sync orders execution only.
// Fallback: if cooperative launch is rejected, classic 2-kernel path.
#define IN_FEAT 512
#define OUT_FEAT 512
#define NTOK 8192
#define KDIM 4096

typedef short bf16x8 __attribute__((ext_vector_type(8)));
typedef float f32x16 __attribute__((ext_vector_type(16)));

static __device__ inline short f2bf(float f) {
    union { float f; unsigned u; } v; v.f = f;
    unsigned u = v.u;
    u += 0x7fffu + ((u >> 16) & 1u);   // RNE
    return (short)(u >> 16);
}

static __device__ inline unsigned cvtpk(float lo, float hi) {
    unsigned r;
    asm("v_cvt_pk_bf16_f32 %0, %1, %2" : "=v"(r) : "v"(lo), "v"(hi));
    return r;
}

// 8 basis features of one (token,input): [silu(xc), xc, T2..T7]
static __device__ inline bf16x8 gen_chunk(float xv) {
    float xc = fminf(fmaxf(xv, -1.f), 1.f);
    float e  = __expf(-xc);
    float bse = xc * __builtin_amdgcn_rcpf(1.f + e);
    float b2 = 2.f * xc * xc - 1.f;
    float b3 = 2.f * xc * b2 - 1.f;
    float b4 = 2.f * xc * b3 - 1.f;
    float b5 = 2.f * xc * b4 - 1.f;
    float b6 = 2.f * xc * b5 - 1.f;
    float b7 = 2.f * xc * b6 - 1.f;
    union { uint4 u; bf16x8 v; } r;
    r.u.x = cvtpk(bse, xc);
    r.u.y = cvtpk(b2, b3);
    r.u.z = cvtpk(b4, b5);
    r.u.w = cvtpk(b6, b7);
    return r.v;
}

static __device__ inline void gload_lds16(const short* g, short* l) {
    __builtin_amdgcn_global_load_lds(
        (const __attribute__((address_space(1))) unsigned int*)g,
        (__attribute__((address_space(3))) unsigned int*)l,
        16, 0, 0);
}

// ---------------- prep phase: W bf16 row o + folded bias[o] ----------------
// o = (bid&7)*64 + (bid>>3): XCD k8 produces exactly rows [k8*64, k8*64+64),
// which is what its gemm phase consumes (nb = k8). red = 16 B of the pool.
static __device__ __forceinline__ void prep_body(
    const float* __restrict__ coeff, const float* __restrict__ scale_base,
    const float* __restrict__ scale_spline, const float* __restrict__ base_bias,
    short* __restrict__ Wb, float* __restrict__ bias, float* red)
{
    int o = (blockIdx.x & 7) * 64 + (blockIdx.x >> 3);
    int tid = threadIdx.x;
    float local = 0.f;
#pragma unroll
    for (int rep = 0; rep < 2; ++rep) {
        int i = tid + rep * 256;
        size_t oi = (size_t)o * IN_FEAT + i;
        const float4* c4 = (const float4*)(coeff + oi * 8);
        float4 ca = c4[0], cb = c4[1];
        float ss = scale_spline[oi];
        float sb = scale_base[oi];
        local += base_bias[oi] + ss * ca.x;
        bf16x8 w;
        w[0] = f2bf(sb);
        w[1] = f2bf(ss * ca.y); w[2] = f2bf(ss * ca.z); w[3] = f2bf(ss * ca.w);
        w[4] = f2bf(ss * cb.x); w[5] = f2bf(ss * cb.y); w[6] = f2bf(ss * cb.z);
        w[7] = f2bf(ss * cb.w);
        *(bf16x8*)(Wb + (size_t)o * KDIM + (size_t)i * 8) = w;
    }
    for (int off = 32; off > 0; off >>= 1) local += __shfl_down(local, off, 64);
    int lane = tid & 63, wv = tid >> 6;
    if (lane == 0) red[wv] = local;
    __syncthreads();
    if (tid == 0) bias[o] = red[0] + red[1] + red[2] + red[3];
}

// ------- gemm phase: verbatim R17 body (59.7us), mapping mb=t, nb=k8 -------
static __device__ __forceinline__ void gemm_body(
    const float* __restrict__ x, const short* __restrict__ Wb,
    const float* __restrict__ bias, float* __restrict__ out, short* POOL)
{
    short* Bs = POOL;                     // [2][16384] shorts, 64 KB

    int tid = threadIdx.x;
    int bid = blockIdx.x;
    int k8 = bid & 7, t = bid >> 3;       // XCD = k8 (HW round-robin)
    int mb = t, nb = k8;                  // W slab [nb*64,+64) is XCD-local
    int m0 = mb * 128, o0 = nb * 64;

    int lane = tid & 63, wv = tid >> 6;
    int kk = wv;                          // wave = 128m x 64n on K-quarter kk
    int l31 = lane & 31, half = lane >> 5;

    f32x16 acc[4][2];                     // [token-group][fn], 32x32 each
#pragma unroll
    for (int a = 0; a < 4; ++a)
#pragma unroll
        for (int b = 0; b < 2; ++b) acc[a][b] = (f32x16)0.f;

    // B DMA: wave wv stages rows [wv*16,+16) x 32 slots, 8 calls of 2 rows.
    // phys slot i&31 holds logical g = (i&31) ^ (row&31); source pre-swizzled.
    int rl2 = lane >> 5, q32 = lane & 31;
    const short* pB[8];
#pragma unroll
    for (int c = 0; c < 8; ++c) {
        int row = wv * 16 + c * 2 + rl2;
        int g = q32 ^ (row & 31);
        pB[c] = Wb + (size_t)(o0 + row) * KDIM + (size_t)g * 8;
    }
    int bd0 = wv * 4096;                  // shorts offset of wave's rows

    // x: wave kk consumes cols [kk*8,+8) of each 32-col K-block; four token
    // groups (m0 + g*32 + l31) -> 2 aligned float4 per group per iter.
    const float* xp0 = x + (size_t)(m0 + l31) * IN_FEAT + kk * 8;

    int ofr[4];
#pragma unroll
    for (int j = 0; j < 4; ++j)
        ofr[j] = l31 * 256 + (((kk * 8 + 2 * j + half) ^ l31) * 8);

#define MFMA_(A, B, C) __builtin_amdgcn_mfma_f32_32x32x16_bf16(A, B, C, 0, 0, 0)

#define GENSEL(Qa, Qb, J) ((J) == 0 ? (half ? (Qa).y : (Qa).x)                \
                         : (J) == 1 ? (half ? (Qa).w : (Qa).z)                \
                         : (J) == 2 ? (half ? (Qb).y : (Qb).x)                \
                                    : (half ? (Qb).w : (Qb).z))

#define STAGE(BUF, IT, Q0a, Q0b, Q1a, Q1b, Q2a, Q2b, Q3a, Q3b)                \
    {                                                                         \
        short* bd_ = Bs + (BUF) * 16384 + bd0;                                \
        const size_t bo_ = (size_t)(IT) * 256;                                \
        _Pragma("unroll")                                                     \
        for (int c_ = 0; c_ < 8; ++c_)                                        \
            gload_lds16(pB[c_] + bo_, bd_ + c_ * 512);                        \
        const float* xq_ = xp0 + (size_t)(IT) * 32;                           \
        Q0a = *(const float4*)(xq_);          Q0b = *(const float4*)(xq_ + 4);          \
        Q1a = *(const float4*)(xq_ + 16384);  Q1b = *(const float4*)(xq_ + 16388);      \
        Q2a = *(const float4*)(xq_ + 32768);  Q2b = *(const float4*)(xq_ + 32772);      \
        Q3a = *(const float4*)(xq_ + 49152);  Q3b = *(const float4*)(xq_ + 49156);      \
    }

#define COMPUTE(CUR, Q0a, Q0b, Q1a, Q1b, Q2a, Q2b, Q3a, Q3b)                  \
    {                                                                         \
        const short* Bc_ = Bs + (CUR) * 16384;                                \
        _Pragma("unroll")                                                     \
        for (int j_ = 0; j_ < 4; ++j_) {                                      \
            bf16x8 b0_ = *(const bf16x8*)(Bc_ + ofr[j_]);                     \
            bf16x8 b1_ = *(const bf16x8*)(Bc_ + ofr[j_] + 8192);              \
            bf16x8 a0_ = gen_chunk(GENSEL(Q0a, Q0b, j_));                     \
            bf16x8 a1_ = gen_chunk(GENSEL(Q1a, Q1b, j_));                     \
            bf16x8 a2_ = gen_chunk(GENSEL(Q2a, Q2b, j_));                     \
            bf16x8 a3_ = gen_chunk(GENSEL(Q3a, Q3b, j_));                     \
            acc[0][0] = MFMA_(a0_, b0_, acc[0][0]); acc[0][1] = MFMA_(a0_, b1_, acc[0][1]); \
            acc[1][0] = MFMA_(a1_, b0_, acc[1][0]); acc[1][1] = MFMA_(a1_, b1_, acc[1][1]); \
            acc[2][0] = MFMA_(a2_, b0_, acc[2][0]); acc[2][1] = MFMA_(a2_, b1_, acc[2][1]); \
            acc[3][0] = MFMA_(a3_, b0_, acc[3][0]); acc[3][1] = MFMA_(a3_, b1_, acc[3][1]); \
        }                                                                     \
    }

    float4 A0a, A0b, A1a, A1b, A2a, A2b, A3a, A3b;
    float4 B0a, B0b, B1a, B1b, B2a, B2b, B3a, B3b;

    STAGE(0, 0, A0a, A0b, A1a, A1b, A2a, A2b, A3a, A3b);
    for (int jj = 0; jj < 8; ++jj) {
        __syncthreads();
        STAGE(1, 2 * jj + 1, B0a, B0b, B1a, B1b, B2a, B2b, B3a, B3b);
        COMPUTE(0, A0a, A0b, A1a, A1b, A2a, A2b, A3a, A3b);
        __syncthreads();
        if (jj < 7)
            STAGE(0, 2 * jj + 2, A0a, A0b, A1a, A1b, A2a, A2b, A3a, A3b);
        COMPUTE(1, B0a, B0b, B1a, B1b, B2a, B2b, B3a, B3b);
    }
#undef STAGE
#undef COMPUTE
#undef GENSEL
#undef MFMA_

    // ---- epilogue: 4-way split-K reduce, two fm-pair passes (verbatim) ----
    float* rbuf = (float*)POOL;           // 16384 floats; max used 8445
#pragma unroll
    for (int p = 0; p < 2; ++p) {
        __syncthreads();
        if (kk >= 2) {
            float* s_ = rbuf + (size_t)(kk - 2) * 4224 + lane * 66;
#pragma unroll
            for (int fm = 0; fm < 2; ++fm)
#pragma unroll
                for (int fn = 0; fn < 2; ++fn)
#pragma unroll
                    for (int r = 0; r < 16; ++r)
                        s_[(fm * 2 + fn) * 16 + r] = acc[2 * p + fm][fn][r];
        }
        __syncthreads();
        if (kk < 2) {
            const float* s_ = rbuf + (size_t)kk * 4224 + lane * 66;
#pragma unroll
            for (int fm = 0; fm < 2; ++fm)
#pragma unroll
                for (int fn = 0; fn < 2; ++fn)
#pragma unroll
                    for (int r = 0; r < 16; ++r)
                        acc[2 * p + fm][fn][r] += s_[(fm * 2 + fn) * 16 + r];
        }
        __syncthreads();
        if (kk == 1) {
            float* s_ = rbuf + lane * 66;
#pragma unroll
            for (int fm = 0; fm < 2; ++fm)
#pragma unroll
                for (int fn = 0; fn < 2; ++fn)
#pragma unroll
                    for (int r = 0; r < 16; ++r)
                        s_[(fm * 2 + fn) * 16 + r] = acc[2 * p + fm][fn][r];
        }
        __syncthreads();
        if (kk == 0) {
            const float* s_ = rbuf + lane * 66;
            // C/D layout (32x32): col = lane&31, row = (r&3)+8*(r>>2)+4*(lane>>5)
#pragma unroll
            for (int fn = 0; fn < 2; ++fn) {
                int o = o0 + fn * 32 + l31;
                float bv = bias[o];
#pragma unroll
                for (int fm = 0; fm < 2; ++fm) {
#pragma unroll
                    for (int r = 0; r < 16; ++r) {
                        float v = acc[2 * p + fm][fn][r] + s_[(fm * 2 + fn) * 16 + r] + bv;
                        int token = m0 + (2 * p + fm) * 32 + (r & 3) + 8 * (r >> 2) + 4 * half;
                        out[(size_t)token * OUT_FEAT + o] = v;
                    }
                }
            }
        }
    }
}

// ---------------- fused cooperative kernel ----------------
__global__ __launch_bounds__(256, 2) void kan_fused(
    const float* __restrict__ x, const float* __restrict__ coeff,
    const float* __restrict__ scale_base, const float* __restrict__ scale_spline,
    const float* __restrict__ base_bias, short* __restrict__ Wb,
    float* __restrict__ bias, float* __restrict__ out)
{
    __shared__ __align__(16) short POOL[32768];   // 64 KB, shared by phases
    prep_body(coeff, scale_base, scale_spline, base_bias, Wb, bias, (float*)POOL);
    cg::this_grid().sync();
    gemm_body(x, Wb, bias, out, POOL);
}

// ---------------- fallback (non-cooperative) kernels ----------------
__global__ __launch_bounds__(256) void kan_prep_fb(
    const float* __restrict__ coeff, const float* __restrict__ scale_base,
    const float* __restrict__ scale_spline, const float* __restrict__ base_bias,
    short* __restrict__ Wb, float* __restrict__ bias)
{
    __shared__ float red[4];
    prep_body(coeff, scale_base, scale_spline, base_bias, Wb, bias, red);
}

__global__ __launch_bounds__(256, 2) void kan_gemm_fb(
    const float* __restrict__ x, const short* __restrict__ Wb,
    const float* __restrict__ bias, float* __restrict__ out)
{
    __shared__ __align__(16) short POOL[32768];
    gemm_body(x, Wb, bias, out, POOL);
}

extern "C" void kernel_launch(void* const* d_in, const int* in_sizes, int n_in,
                              void* d_out, int out_size, void* d_ws, size_t ws_size,
                              hipStream_t stream) {
    const float* x            = (const float*)d_in[0];
    const float* coeff        = (const float*)d_in[1];
    const float* scale_base   = (const float*)d_in[2];
    const float* scale_spline = (const float*)d_in[3];
    const float* base_bias    = (const float*)d_in[4];
    float* out = (float*)d_out;

    short* Wb   = (short*)d_ws;                                  // 4 MB
    float* bias = (float*)((char*)d_ws + (size_t)OUT_FEAT * KDIM * 2);

    void* args[] = { (void*)&x, (void*)&coeff, (void*)&scale_base,
                     (void*)&scale_spline, (void*)&base_bias,
                     (void*)&Wb, (void*)&bias, (void*)&out };
    hipError_t e = hipLaunchCooperativeKernel((const void*)kan_fused,
                                              dim3(512), dim3(256),
                                              args, 0, stream);
    if (e != hipSuccess) {               // capture/coop rejected -> 2-kernel path
        (void)hipGetLastError();         // clear sticky error
        kan_prep_fb<<<512, 256, 0, stream>>>(coeff, scale_base, scale_spline,
                                             base_bias, Wb, bias);
        kan_gemm_fb<<<512, 256, 0, stream>>>(x, Wb, bias, out);
    }
}